// Round 4
// baseline (233.784 us; speedup 1.0000x reference)
//
#include <hip/hip_runtime.h>
#include <math.h>

// B=4, N=256, D=256, H=8, DK=32, DV=32, R=64
constexpr int B_ = 4, N_ = 256, D_ = 256, H_ = 8, DK_ = 32, DV_ = 32, R_ = 64;
constexpr float SCALE_ = 0.17677669529663687f;  // 1/sqrt(32)
constexpr float EPS_ = 1e-6f;

// ---------------------------------------------------------------------------
// K1: fused projection GEMM, 200 blocks:
//   blocks 0..191 : [1024 x 768] = q[1024,256] @ cat(Wq,Wk,Wv) -> Xq,Xk,Xv
//   blocks 192..199: [64 x 512]  = relE[64,256] @ cat(Wr,Wvv)  -> Ek,Ev
// 64x64 tile, 16x16 threads, 4x4 acc.
__global__ __launch_bounds__(256) void projekev_kernel(
        const float* __restrict__ q, const float* __restrict__ Wq,
        const float* __restrict__ Wk, const float* __restrict__ Wv,
        const float* __restrict__ relE, const float* __restrict__ Wr,
        const float* __restrict__ Wvv, float* __restrict__ Xq,
        float* __restrict__ Xk, float* __restrict__ Xv,
        float* __restrict__ Ek, float* __restrict__ Ev) {
    int blk = blockIdx.x;
    int t = threadIdx.x;
    __shared__ __align__(16) float ash[32 * 65];
    __shared__ __align__(16) float bsh[32 * 64];
    const float *src, *W;
    int rowbase, cbase, ct;
    float* dstE = nullptr;
    if (blk < 192) {
        ct = blk >> 4;
        int rt = blk & 15;
        src = q; rowbase = rt * 64;
        if (ct < 4)      { W = Wq; cbase = ct * 64; }
        else if (ct < 8) { W = Wk; cbase = (ct - 4) * 64; }
        else             { W = Wv; cbase = (ct - 8) * 64; }
    } else {
        int e = blk - 192;           // 0..7
        src = relE; rowbase = 0; ct = -1;
        W = (e < 4) ? Wr : Wvv;
        dstE = (e < 4) ? Ek : Ev;
        cbase = (e & 3) * 64;
    }
    int ti = t >> 4, tj = t & 15;
    float acc[4][4] = {{0.f}};
    for (int kc = 0; kc < 8; ++kc) {
        __syncthreads();
#pragma unroll
        for (int kk = 0; kk < 2; ++kk) {
            int m = t + kk * 256;
            int i = m >> 3, kq = m & 7;
            float4 v = *(const float4*)(src + (size_t)(rowbase + i) * 256 + kc * 32 + kq * 4);
            ash[(kq * 4 + 0) * 65 + i] = v.x;
            ash[(kq * 4 + 1) * 65 + i] = v.y;
            ash[(kq * 4 + 2) * 65 + i] = v.z;
            ash[(kq * 4 + 3) * 65 + i] = v.w;
        }
#pragma unroll
        for (int kk = 0; kk < 2; ++kk) {
            int m = t + kk * 256;
            int k = m >> 4, j4 = m & 15;
            float4 v = *(const float4*)(W + (size_t)(kc * 32 + k) * 256 + cbase + j4 * 4);
            *(float4*)(bsh + k * 64 + j4 * 4) = v;
        }
        __syncthreads();
#pragma unroll 8
        for (int k = 0; k < 32; ++k) {
            float4 av = *(const float4*)(ash + k * 65 + ti * 4);
            float4 bv = *(const float4*)(bsh + k * 64 + tj * 4);
            acc[0][0] += av.x * bv.x; acc[0][1] += av.x * bv.y;
            acc[0][2] += av.x * bv.z; acc[0][3] += av.x * bv.w;
            acc[1][0] += av.y * bv.x; acc[1][1] += av.y * bv.y;
            acc[1][2] += av.y * bv.z; acc[1][3] += av.y * bv.w;
            acc[2][0] += av.z * bv.x; acc[2][1] += av.z * bv.y;
            acc[2][2] += av.z * bv.z; acc[2][3] += av.z * bv.w;
            acc[3][0] += av.w * bv.x; acc[3][1] += av.w * bv.y;
            acc[3][2] += av.w * bv.z; acc[3][3] += av.w * bv.w;
        }
    }
    if (dstE) {
#pragma unroll
        for (int a = 0; a < 4; ++a) {
            int row = ti * 4 + a;
            *(float4*)(dstE + (size_t)row * 256 + cbase + tj * 4) =
                make_float4(acc[a][0], acc[a][1], acc[a][2], acc[a][3]);
        }
    } else {
        float* dst = (ct < 4) ? Xq : (ct < 8) ? Xk : Xv;
        int gcol = (ct & 3) * 64 + tj * 4;
        int h = gcol >> 5, dk = gcol & 31;
#pragma unroll
        for (int a = 0; a < 4; ++a) {
            int row = rowbase + ti * 4 + a;
            int bb = row >> 8, n = row & 255;
            *(float4*)(dst + ((size_t)(bb * 8 + h) * 256 + n) * 32 + dk) =
                make_float4(acc[a][0], acc[a][1], acc[a][2], acc[a][3]);
        }
    }
}

// ---------------------------------------------------------------------------
// K2: one block per (b,i) row — T, qk, bias, softmax, S, Z, Wo+LN all fused.
// grid = 1024, block = 256 (4 waves). LDS ~20 KB.
__global__ __launch_bounds__(256) void biassmzout_kernel(
        const float* __restrict__ link, const float* __restrict__ Ek,
        const float* __restrict__ Ev, const float* __restrict__ Xq,
        const float* __restrict__ Xk, const float* __restrict__ Xv,
        const int* __restrict__ mask, const float* __restrict__ Wo,
        const float* __restrict__ q, const float* __restrict__ gamma,
        const float* __restrict__ beta, float* __restrict__ alpha,
        float* __restrict__ out) {
    // bijective XCD swizzle (1024 = 8*128): XCD k owns bi in [128k, 128k+128)
    int bi = ((blockIdx.x & 7) << 7) | (blockIdx.x >> 3);
    int b = bi >> 8, i = bi & 255;
    int t = threadIdx.x;
    int lane = t & 63, g = t >> 6;

    __shared__ __align__(16) float xqsh[256];    // Xq row, all 8 heads
    __shared__ __align__(16) float Tsh[8 * 68];  // T (padded rows); later S
    __shared__ __align__(16) float ashm[8 * 260];// alpha (padded); later zsh
    __shared__ __align__(16) float part[2048];   // S partials; later Z partials
    __shared__ float redsh[64];

    // tiny first-touch loads
    float resid = q[(size_t)bi * 256 + t];
    int mv = mask[((size_t)(b * 256 + i)) * 256 + t];
    xqsh[t] = Xq[((size_t)(b * 8 + (t >> 5)) * 256 + i) * 32 + (t & 31)];
    __syncthreads();                                            // B1

    // ---- prefetch bias link row (16 KB/block, the cold HBM read) ----
    // issued first; T/qk global loads queue behind it so its latency hides.
    float4 lk[16];
    {
        const float4* l4 = (const float4*)(link + ((size_t)(bi * 256 + t)) * 64);
#pragma unroll
        for (int k = 0; k < 16; ++k) lk[k] = l4[k];
    }

    // ---- T: Tsh[h][r] = sum_dk Xq[b,h,i,dk] * Ek[r, h*32+dk] ----
#pragma unroll
    for (int hr = t; hr < 512; hr += 256) {
        int h = hr >> 6, r = hr & 63;
        const float4* e4 = (const float4*)(Ek + r * 256 + h * 32);
        const float4* x4 = (const float4*)(xqsh + h * 32);
        float acc = 0.f;
#pragma unroll
        for (int k = 0; k < 8; ++k) {
            float4 e = e4[k], x = x4[k];
            acc += e.x * x.x + e.y * x.y + e.z * x.z + e.w * x.w;
        }
        Tsh[h * 68 + r] = acc;
    }

    // ---- qk: s[h] = Xq[b,h,i,:].Xk[b,h,j=t,:]  (Xk L2-hot via XCD swizzle)
    float s[8];
#pragma unroll 2
    for (int h = 0; h < 8; ++h) {
        const float4* k4 = (const float4*)(Xk + (((size_t)(b * 8 + h)) * 256 + t) * 32);
        const float4* x4 = (const float4*)(xqsh + h * 32);
        float acc = 0.f;
#pragma unroll
        for (int k = 0; k < 8; ++k) {
            float4 kv = k4[k], xv = x4[k];
            acc += kv.x * xv.x + kv.y * xv.y + kv.z * xv.z + kv.w * xv.w;
        }
        s[h] = acc;
    }
    __syncthreads();                                            // B2 (Tsh ready)

    // ---- bias: s[h] += sum_r link[bi,t,r] * T[h][r]  (lk in regs, T in LDS)
    {
        const float4* T4 = (const float4*)Tsh;   // row stride 17 float4s
#pragma unroll 8
        for (int k = 0; k < 16; ++k) {
            float4 lv = lk[k];
#pragma unroll
            for (int h = 0; h < 8; ++h) {
                float4 tv = T4[h * 17 + k];
                s[h] += lv.x * tv.x + lv.y * tv.y + lv.z * tv.z + lv.w * tv.w;
            }
        }
    }
#pragma unroll
    for (int h = 0; h < 8; ++h) {
        s[h] *= SCALE_;
        if (mv == 0) s[h] = -1e9f;
    }

    // ---- prefetch S-phase link (lane=r, wave g owns j-chunk): latency hides
    //      under the softmax shuffles below.
    float lreg[64];
    {
        const float* lp = link + ((size_t)(bi * 256 + g * 64)) * 64 + lane;
#pragma unroll
        for (int jj = 0; jj < 64; ++jj) lreg[jj] = lp[jj * 64];
    }
    __builtin_amdgcn_sched_barrier(0);  // keep the issue point here

    // ---- softmax over j (thread = j) ----
#pragma unroll
    for (int h = 0; h < 8; ++h) {
        float v = s[h];
        for (int off = 32; off > 0; off >>= 1) v = fmaxf(v, __shfl_xor(v, off));
        if (lane == 0) redsh[h * 4 + g] = v;
    }
    __syncthreads();                                            // B3
    float mx[8];
#pragma unroll
    for (int h = 0; h < 8; ++h)
        mx[h] = fmaxf(fmaxf(redsh[h * 4 + 0], redsh[h * 4 + 1]),
                      fmaxf(redsh[h * 4 + 2], redsh[h * 4 + 3]));
#pragma unroll
    for (int h = 0; h < 8; ++h) {
        float e = __expf(s[h] - mx[h]);
        s[h] = e;
        float v = e;
        for (int off = 32; off > 0; off >>= 1) v += __shfl_xor(v, off);
        if (lane == 0) redsh[32 + h * 4 + g] = v;
    }
    __syncthreads();                                            // B4
#pragma unroll
    for (int h = 0; h < 8; ++h) {
        float esum = redsh[32 + h * 4 + 0] + redsh[32 + h * 4 + 1] +
                     redsh[32 + h * 4 + 2] + redsh[32 + h * 4 + 3];
        float a = s[h] * (1.f / esum);
        ashm[h * 260 + t] = a;
        alpha[((size_t)(b * 8 + h) * 256 + i) * 256 + t] = a;
    }
    __syncthreads();                                            // B5 (alpha)

    // ---- S partials from registers: S[h,r] += alpha[h,j]*link[j,r] ----
    {
        float pacc[8] = {0.f, 0.f, 0.f, 0.f, 0.f, 0.f, 0.f, 0.f};
#pragma unroll
        for (int j4 = 0; j4 < 16; ++j4) {
#pragma unroll
            for (int h = 0; h < 8; ++h) {
                float4 a = *(const float4*)(ashm + h * 260 + g * 64 + j4 * 4);
                pacc[h] += a.x * lreg[j4 * 4 + 0] + a.y * lreg[j4 * 4 + 1] +
                           a.z * lreg[j4 * 4 + 2] + a.w * lreg[j4 * 4 + 3];
            }
        }
#pragma unroll
        for (int h = 0; h < 8; ++h) part[g * 512 + h * 64 + lane] = pacc[h];
    }
    __syncthreads();                                            // B6
    for (int hr = t; hr < 512; hr += 256)
        Tsh[(hr >> 6) * 68 + (hr & 63)] =
            part[hr] + part[512 + hr] + part[1024 + hr] + part[1536 + hr];
    __syncthreads();                                            // B7 (S ready)

    // ---- Z (vectorized): lane l -> (h=l>>3, dv4=l&7); wave g owns j,r chunks
    {
        int h = lane >> 3, dv4 = lane & 7;
        const float4* xv4 = (const float4*)Xv + (((size_t)(b * 8 + h)) * 256 + g * 64) * 8 + dv4;
        const float* ap = ashm + h * 260 + g * 64;
        float4 z = make_float4(0.f, 0.f, 0.f, 0.f);
#pragma unroll 8
        for (int j = 0; j < 64; ++j) {
            float a = ap[j];
            float4 x = xv4[j * 8];
            z.x += a * x.x; z.y += a * x.y; z.z += a * x.z; z.w += a * x.w;
        }
        const float4* ev4 = (const float4*)Ev + (g * 16) * 64 + h * 8 + dv4;
        const float* sp = Tsh + h * 68 + g * 16;
#pragma unroll
        for (int r = 0; r < 16; ++r) {
            float sv = sp[r];
            float4 e = ev4[r * 64];
            z.x += sv * e.x; z.y += sv * e.y; z.z += sv * e.z; z.w += sv * e.w;
        }
        ((float4*)part)[g * 64 + lane] = z;
    }
    __syncthreads();                                            // B8
    // assemble Z row into ashm[0..255] (alpha dead)
    {
        float zv = part[t] + part[256 + t] + part[512 + t] + part[768 + t];
        ashm[t] = zv;
    }
    __syncthreads();                                            // B9

    // ---- out = LN(Z @ Wo + q) ----
    float a = resid;
    {
        const float4* z4 = (const float4*)ashm;
        const float* wp = Wo + t;
#pragma unroll 4
        for (int d4 = 0; d4 < 64; ++d4) {
            float4 zz = z4[d4];
            a += zz.x * wp[(d4 * 4 + 0) * 256] + zz.y * wp[(d4 * 4 + 1) * 256] +
                 zz.z * wp[(d4 * 4 + 2) * 256] + zz.w * wp[(d4 * 4 + 3) * 256];
        }
    }
    {
        float v = a, v2 = a * a;
        for (int off = 32; off > 0; off >>= 1) {
            v += __shfl_xor(v, off);
            v2 += __shfl_xor(v2, off);
        }
        if (lane == 0) { redsh[g] = v; redsh[8 + g] = v2; }
    }
    __syncthreads();                                            // B10
    {
        float sum = redsh[0] + redsh[1] + redsh[2] + redsh[3];
        float sum2 = redsh[8] + redsh[9] + redsh[10] + redsh[11];
        float mu = sum * (1.f / 256.f);
        float var = sum2 * (1.f / 256.f) - mu * mu;
        out[(size_t)bi * 256 + t] = (a - mu) * rsqrtf(var + EPS_) * gamma[t] + beta[t];
    }
}

// ---------------------------------------------------------------------------
extern "C" void kernel_launch(void* const* d_in, const int* in_sizes, int n_in,
                              void* d_out, int out_size, void* d_ws, size_t ws_size,
                              hipStream_t stream) {
    const float* q     = (const float*)d_in[0];
    const int*   mask  = (const int*)d_in[3];
    const float* link  = (const float*)d_in[4];
    const float* Wq    = (const float*)d_in[5];
    const float* Wk    = (const float*)d_in[6];
    const float* Wr    = (const float*)d_in[7];
    const float* Wv    = (const float*)d_in[8];
    const float* Wvv   = (const float*)d_in[9];
    const float* relE  = (const float*)d_in[10];
    const float* Wo    = (const float*)d_in[11];
    const float* gamma = (const float*)d_in[12];
    const float* beta  = (const float*)d_in[13];

    float* out   = (float*)d_out;
    float* alpha = out + B_ * N_ * D_;      // second output [B,H,N,N]

    float* ws = (float*)d_ws;
    float* Ek = ws;                 // 16384
    float* Ev = Ek + 16384;         // 16384
    float* Xq = Ev + 16384;         // 262144
    float* Xk = Xq + 262144;        // 262144
    float* Xv = Xk + 262144;        // 262144  (total ~3.3 MB)

    projekev_kernel<<<200, 256, 0, stream>>>(q, Wq, Wk, Wv, relE, Wr, Wvv,
                                             Xq, Xk, Xv, Ek, Ev);
    biassmzout_kernel<<<1024, 256, 0, stream>>>(link, Ek, Ev, Xq, Xk, Xv, mask,
                                                Wo, q, gamma, beta, alpha, out);
}

// Round 5
// 201.839 us; speedup vs baseline: 1.1583x; 1.1583x over previous
//
#include <hip/hip_runtime.h>
#include <math.h>

// B=4, N=256, D=256, H=8, DK=32, DV=32, R=64
constexpr int B_ = 4, N_ = 256, D_ = 256, H_ = 8, DK_ = 32, DV_ = 32, R_ = 64;
constexpr float SCALE_ = 0.17677669529663687f;  // 1/sqrt(32)
constexpr float EPS_ = 1e-6f;

// ---------------------------------------------------------------------------
// K1: fused projection GEMM, 200 blocks:
//   blocks 0..191 : [1024 x 768] = q[1024,256] @ cat(Wq,Wk,Wv) -> Xq,Xk,Xv
//   blocks 192..199: [64 x 512]  = relE[64,256] @ cat(Wr,Wvv)  -> Ek,Ev
// 64x64 tile, 16x16 threads, 4x4 acc.
__global__ __launch_bounds__(256) void projekev_kernel(
        const float* __restrict__ q, const float* __restrict__ Wq,
        const float* __restrict__ Wk, const float* __restrict__ Wv,
        const float* __restrict__ relE, const float* __restrict__ Wr,
        const float* __restrict__ Wvv, float* __restrict__ Xq,
        float* __restrict__ Xk, float* __restrict__ Xv,
        float* __restrict__ Ek, float* __restrict__ Ev) {
    int blk = blockIdx.x;
    int t = threadIdx.x;
    __shared__ __align__(16) float ash[32 * 65];
    __shared__ __align__(16) float bsh[32 * 64];
    const float *src, *W;
    int rowbase, cbase, ct;
    float* dstE = nullptr;
    if (blk < 192) {
        ct = blk >> 4;
        int rt = blk & 15;
        src = q; rowbase = rt * 64;
        if (ct < 4)      { W = Wq; cbase = ct * 64; }
        else if (ct < 8) { W = Wk; cbase = (ct - 4) * 64; }
        else             { W = Wv; cbase = (ct - 8) * 64; }
    } else {
        int e = blk - 192;           // 0..7
        src = relE; rowbase = 0; ct = -1;
        W = (e < 4) ? Wr : Wvv;
        dstE = (e < 4) ? Ek : Ev;
        cbase = (e & 3) * 64;
    }
    int ti = t >> 4, tj = t & 15;
    float acc[4][4] = {{0.f}};
    for (int kc = 0; kc < 8; ++kc) {
        __syncthreads();
#pragma unroll
        for (int kk = 0; kk < 2; ++kk) {
            int m = t + kk * 256;
            int i = m >> 3, kq = m & 7;
            float4 v = *(const float4*)(src + (size_t)(rowbase + i) * 256 + kc * 32 + kq * 4);
            ash[(kq * 4 + 0) * 65 + i] = v.x;
            ash[(kq * 4 + 1) * 65 + i] = v.y;
            ash[(kq * 4 + 2) * 65 + i] = v.z;
            ash[(kq * 4 + 3) * 65 + i] = v.w;
        }
#pragma unroll
        for (int kk = 0; kk < 2; ++kk) {
            int m = t + kk * 256;
            int k = m >> 4, j4 = m & 15;
            float4 v = *(const float4*)(W + (size_t)(kc * 32 + k) * 256 + cbase + j4 * 4);
            *(float4*)(bsh + k * 64 + j4 * 4) = v;
        }
        __syncthreads();
#pragma unroll 8
        for (int k = 0; k < 32; ++k) {
            float4 av = *(const float4*)(ash + k * 65 + ti * 4);
            float4 bv = *(const float4*)(bsh + k * 64 + tj * 4);
            acc[0][0] += av.x * bv.x; acc[0][1] += av.x * bv.y;
            acc[0][2] += av.x * bv.z; acc[0][3] += av.x * bv.w;
            acc[1][0] += av.y * bv.x; acc[1][1] += av.y * bv.y;
            acc[1][2] += av.y * bv.z; acc[1][3] += av.y * bv.w;
            acc[2][0] += av.z * bv.x; acc[2][1] += av.z * bv.y;
            acc[2][2] += av.z * bv.z; acc[2][3] += av.z * bv.w;
            acc[3][0] += av.w * bv.x; acc[3][1] += av.w * bv.y;
            acc[3][2] += av.w * bv.z; acc[3][3] += av.w * bv.w;
        }
    }
    if (dstE) {
#pragma unroll
        for (int a = 0; a < 4; ++a) {
            int row = ti * 4 + a;
            *(float4*)(dstE + (size_t)row * 256 + cbase + tj * 4) =
                make_float4(acc[a][0], acc[a][1], acc[a][2], acc[a][3]);
        }
    } else {
        float* dst = (ct < 4) ? Xq : (ct < 8) ? Xk : Xv;
        int gcol = (ct & 3) * 64 + tj * 4;
        int h = gcol >> 5, dk = gcol & 31;
#pragma unroll
        for (int a = 0; a < 4; ++a) {
            int row = rowbase + ti * 4 + a;
            int bb = row >> 8, n = row & 255;
            *(float4*)(dst + ((size_t)(bb * 8 + h) * 256 + n) * 32 + dk) =
                make_float4(acc[a][0], acc[a][1], acc[a][2], acc[a][3]);
        }
    }
}

// ---------------------------------------------------------------------------
// K2: one block per (b,i) row — T, qk, bias, softmax, S, Z, Wo+LN all fused.
// grid = 1024, block = 256 (4 waves). LDS ~20 KB.
// NO per-thread register arrays for link (round-4 spilled 65 MB to scratch);
// link is read directly from global in both the bias and S phases — the
// round-3 pattern that ran clean at 60 VGPR. launch_bounds(256,4) matches the
// grid-cap occupancy (4 blocks/CU) and gives the allocator ~128 VGPRs.
__global__ __launch_bounds__(256, 4) void biassmzout_kernel(
        const float* __restrict__ link, const float* __restrict__ Ek,
        const float* __restrict__ Ev, const float* __restrict__ Xq,
        const float* __restrict__ Xk, const float* __restrict__ Xv,
        const int* __restrict__ mask, const float* __restrict__ Wo,
        const float* __restrict__ q, const float* __restrict__ gamma,
        const float* __restrict__ beta, float* __restrict__ alpha,
        float* __restrict__ out) {
    // bijective XCD swizzle (1024 = 8*128): XCD k owns bi in [128k, 128k+128)
    int bi = ((blockIdx.x & 7) << 7) | (blockIdx.x >> 3);
    int b = bi >> 8, i = bi & 255;
    int t = threadIdx.x;
    int lane = t & 63, g = t >> 6;

    __shared__ __align__(16) float xqsh[256];    // Xq row, all 8 heads
    __shared__ __align__(16) float Tsh[8 * 68];  // T (padded rows); later S
    __shared__ __align__(16) float ashm[8 * 260];// alpha (padded); later zsh
    __shared__ __align__(16) float part[2048];   // S partials; later Z partials
    __shared__ float redsh[64];

    // tiny first-touch loads
    float resid = q[(size_t)bi * 256 + t];
    int mv = mask[((size_t)(b * 256 + i)) * 256 + t];
    xqsh[t] = Xq[((size_t)(b * 8 + (t >> 5)) * 256 + i) * 32 + (t & 31)];
    __syncthreads();                                            // B1

    // ---- T: Tsh[h][r] = sum_dk Xq[b,h,i,dk] * Ek[r, h*32+dk] ----
#pragma unroll
    for (int hr = t; hr < 512; hr += 256) {
        int h = hr >> 6, r = hr & 63;
        const float4* e4 = (const float4*)(Ek + r * 256 + h * 32);
        const float4* x4 = (const float4*)(xqsh + h * 32);
        float acc = 0.f;
#pragma unroll
        for (int k = 0; k < 8; ++k) {
            float4 e = e4[k], x = x4[k];
            acc += e.x * x.x + e.y * x.y + e.z * x.z + e.w * x.w;
        }
        Tsh[h * 68 + r] = acc;
    }

    // ---- qk: s[h] = Xq[b,h,i,:].Xk[b,h,j=t,:]  (Xk L2-hot via XCD swizzle)
    float s[8];
#pragma unroll 2
    for (int h = 0; h < 8; ++h) {
        const float4* k4 = (const float4*)(Xk + (((size_t)(b * 8 + h)) * 256 + t) * 32);
        const float4* x4 = (const float4*)(xqsh + h * 32);
        float acc = 0.f;
#pragma unroll
        for (int k = 0; k < 8; ++k) {
            float4 kv = k4[k], xv = x4[k];
            acc += kv.x * xv.x + kv.y * xv.y + kv.z * xv.z + kv.w * xv.w;
        }
        s[h] = acc;
    }
    __syncthreads();                                            // B2 (Tsh ready)

    // ---- bias: s[h] += sum_r link[bi,t,r] * T[h][r]  (link direct, T LDS)
    {
        const float4* l4 = (const float4*)(link + ((size_t)(bi * 256 + t)) * 64);
        const float4* T4 = (const float4*)Tsh;   // row stride 17 float4s
#pragma unroll 8
        for (int k = 0; k < 16; ++k) {
            float4 lv = l4[k];
#pragma unroll
            for (int h = 0; h < 8; ++h) {
                float4 tv = T4[h * 17 + k];
                s[h] += lv.x * tv.x + lv.y * tv.y + lv.z * tv.z + lv.w * tv.w;
            }
        }
    }
#pragma unroll
    for (int h = 0; h < 8; ++h) {
        s[h] *= SCALE_;
        if (mv == 0) s[h] = -1e9f;
    }

    // ---- softmax over j (thread = j) ----
#pragma unroll
    for (int h = 0; h < 8; ++h) {
        float v = s[h];
        for (int off = 32; off > 0; off >>= 1) v = fmaxf(v, __shfl_xor(v, off));
        if (lane == 0) redsh[h * 4 + g] = v;
    }
    __syncthreads();                                            // B3
    float mx[8];
#pragma unroll
    for (int h = 0; h < 8; ++h)
        mx[h] = fmaxf(fmaxf(redsh[h * 4 + 0], redsh[h * 4 + 1]),
                      fmaxf(redsh[h * 4 + 2], redsh[h * 4 + 3]));
#pragma unroll
    for (int h = 0; h < 8; ++h) {
        float e = __expf(s[h] - mx[h]);
        s[h] = e;
        float v = e;
        for (int off = 32; off > 0; off >>= 1) v += __shfl_xor(v, off);
        if (lane == 0) redsh[32 + h * 4 + g] = v;
    }
    __syncthreads();                                            // B4
#pragma unroll
    for (int h = 0; h < 8; ++h) {
        float esum = redsh[32 + h * 4 + 0] + redsh[32 + h * 4 + 1] +
                     redsh[32 + h * 4 + 2] + redsh[32 + h * 4 + 3];
        float a = s[h] * (1.f / esum);
        ashm[h * 260 + t] = a;
        alpha[((size_t)(b * 8 + h) * 256 + i) * 256 + t] = a;
    }
    __syncthreads();                                            // B5 (alpha)

    // ---- S partials (wave g owns j in [64g,64g+64), lane = r; L2/L3-hot) ----
    {
        float pacc[8] = {0.f, 0.f, 0.f, 0.f, 0.f, 0.f, 0.f, 0.f};
        const float* lp2 = link + ((size_t)(bi * 256 + g * 64)) * 64 + lane;
#pragma unroll 4
        for (int j4 = 0; j4 < 16; ++j4) {
            float l0 = lp2[(j4 * 4 + 0) * 64];
            float l1 = lp2[(j4 * 4 + 1) * 64];
            float l2 = lp2[(j4 * 4 + 2) * 64];
            float l3 = lp2[(j4 * 4 + 3) * 64];
#pragma unroll
            for (int h = 0; h < 8; ++h) {
                float4 a = *(const float4*)(ashm + h * 260 + g * 64 + j4 * 4);
                pacc[h] += a.x * l0 + a.y * l1 + a.z * l2 + a.w * l3;
            }
        }
#pragma unroll
        for (int h = 0; h < 8; ++h) part[g * 512 + h * 64 + lane] = pacc[h];
    }
    __syncthreads();                                            // B6
    for (int hr = t; hr < 512; hr += 256)
        Tsh[(hr >> 6) * 68 + (hr & 63)] =
            part[hr] + part[512 + hr] + part[1024 + hr] + part[1536 + hr];
    __syncthreads();                                            // B7 (S ready)

    // ---- Z (vectorized): lane l -> (h=l>>3, dv4=l&7); wave g owns j,r chunks
    {
        int h = lane >> 3, dv4 = lane & 7;
        const float4* xv4 = (const float4*)Xv + (((size_t)(b * 8 + h)) * 256 + g * 64) * 8 + dv4;
        const float* ap = ashm + h * 260 + g * 64;
        float4 z = make_float4(0.f, 0.f, 0.f, 0.f);
#pragma unroll 8
        for (int j = 0; j < 64; ++j) {
            float a = ap[j];
            float4 x = xv4[j * 8];
            z.x += a * x.x; z.y += a * x.y; z.z += a * x.z; z.w += a * x.w;
        }
        const float4* ev4 = (const float4*)Ev + (g * 16) * 64 + h * 8 + dv4;
        const float* sp = Tsh + h * 68 + g * 16;
#pragma unroll
        for (int r = 0; r < 16; ++r) {
            float sv = sp[r];
            float4 e = ev4[r * 64];
            z.x += sv * e.x; z.y += sv * e.y; z.z += sv * e.z; z.w += sv * e.w;
        }
        ((float4*)part)[g * 64 + lane] = z;
    }
    __syncthreads();                                            // B8
    // assemble Z row into ashm[0..255] (alpha dead)
    {
        float zv = part[t] + part[256 + t] + part[512 + t] + part[768 + t];
        ashm[t] = zv;
    }
    __syncthreads();                                            // B9

    // ---- out = LN(Z @ Wo + q) ----
    float a = resid;
    {
        const float4* z4 = (const float4*)ashm;
        const float* wp = Wo + t;
#pragma unroll 4
        for (int d4 = 0; d4 < 64; ++d4) {
            float4 zz = z4[d4];
            a += zz.x * wp[(d4 * 4 + 0) * 256] + zz.y * wp[(d4 * 4 + 1) * 256] +
                 zz.z * wp[(d4 * 4 + 2) * 256] + zz.w * wp[(d4 * 4 + 3) * 256];
        }
    }
    {
        float v = a, v2 = a * a;
        for (int off = 32; off > 0; off >>= 1) {
            v += __shfl_xor(v, off);
            v2 += __shfl_xor(v2, off);
        }
        if (lane == 0) { redsh[g] = v; redsh[8 + g] = v2; }
    }
    __syncthreads();                                            // B10
    {
        float sum = redsh[0] + redsh[1] + redsh[2] + redsh[3];
        float sum2 = redsh[8] + redsh[9] + redsh[10] + redsh[11];
        float mu = sum * (1.f / 256.f);
        float var = sum2 * (1.f / 256.f) - mu * mu;
        out[(size_t)bi * 256 + t] = (a - mu) * rsqrtf(var + EPS_) * gamma[t] + beta[t];
    }
}

// ---------------------------------------------------------------------------
extern "C" void kernel_launch(void* const* d_in, const int* in_sizes, int n_in,
                              void* d_out, int out_size, void* d_ws, size_t ws_size,
                              hipStream_t stream) {
    const float* q     = (const float*)d_in[0];
    const int*   mask  = (const int*)d_in[3];
    const float* link  = (const float*)d_in[4];
    const float* Wq    = (const float*)d_in[5];
    const float* Wk    = (const float*)d_in[6];
    const float* Wr    = (const float*)d_in[7];
    const float* Wv    = (const float*)d_in[8];
    const float* Wvv   = (const float*)d_in[9];
    const float* relE  = (const float*)d_in[10];
    const float* Wo    = (const float*)d_in[11];
    const float* gamma = (const float*)d_in[12];
    const float* beta  = (const float*)d_in[13];

    float* out   = (float*)d_out;
    float* alpha = out + B_ * N_ * D_;      // second output [B,H,N,N]

    float* ws = (float*)d_ws;
    float* Ek = ws;                 // 16384
    float* Ev = Ek + 16384;         // 16384
    float* Xq = Ev + 16384;         // 262144
    float* Xk = Xq + 262144;        // 262144
    float* Xv = Xk + 262144;        // 262144  (total ~3.3 MB)

    projekev_kernel<<<200, 256, 0, stream>>>(q, Wq, Wk, Wv, relE, Wr, Wvv,
                                             Xq, Xk, Xv, Ek, Ev);
    biassmzout_kernel<<<1024, 256, 0, stream>>>(link, Ek, Ev, Xq, Xk, Xv, mask,
                                                Wo, q, gamma, beta, alpha, out);
}